// Round 4
// baseline (9473.335 us; speedup 1.0000x reference)
//
#include <hip/hip_runtime.h>
#include <hip/hip_bf16.h>
#include <math.h>

// CaptionModel: 200-step GRU (B=256,H=512) + projection V=100.
// The recurrence is chaotic: measured amplification ~2e5 over 200 steps
// (round-2 inj 2^-9 -> saturated 0.76; round-3 inj 2^-18 -> 0.707 linear).
// Passing requires f32-exact-or-better per-step arithmetic:
//   - weights & h: 3-way bf16 splits (rep error <= 2^-27)
//   - bf16xbf16 products exact in f32; K=32 chunks accumulated in ZEROED
//     f32 MFMA chains (noise ~2^-24*|chunk|), chunk results summed in f64
//   - gates/biases/tanh/sigmoid/h-carry in f64
// Projection (non-amplified) uses 2-split h x 2-split pw f32 MFMA.

typedef __bf16 bf16_t;
typedef __bf16 bf16x8 __attribute__((ext_vector_type(8)));
typedef float f32x4 __attribute__((ext_vector_type(4)));

#define B_ 256
#define H_ 512
#define V_ 100
#define T_ 200
#define NW_ (3 * H_ * H_)

#define MFMA(a, b, c) __builtin_amdgcn_mfma_f32_16x16x32_bf16((a), (b), (c), 0, 0, 0)

__device__ __forceinline__ float ld_in(const void* p, long i, int isf32) {
    return isf32 ? ((const float*)p)[i] : (float)((const bf16_t*)p)[i];
}

__device__ __forceinline__ void split3f(float v, bf16_t* o1, bf16_t* o2, bf16_t* o3) {
    bf16_t a = (bf16_t)v;        float r1 = v - (float)a;
    bf16_t b = (bf16_t)r1;       float r2 = r1 - (float)b;
    *o1 = a; *o2 = b; *o3 = (bf16_t)r2;
}

__device__ __forceinline__ void split3d(double v, bf16_t* o1, bf16_t* o2, bf16_t* o3) {
    bf16_t a = (bf16_t)(float)v;   double r1 = v - (double)(float)a;
    bf16_t b = (bf16_t)(float)r1;  double r2 = r1 - (double)(float)b;
    *o1 = a; *o2 = b; *o3 = (bf16_t)(float)r2;
}

// ---------------------------------------------------------------------------
__global__ __launch_bounds__(256) void convert_kernel(
    const void* __restrict__ feat, const void* __restrict__ embed,
    const void* __restrict__ wih,  const void* __restrict__ whh,
    const void* __restrict__ bih,  const void* __restrict__ bhh,
    const void* __restrict__ pw,   const void* __restrict__ pb,
    int* __restrict__ flag,
    bf16_t* __restrict__ f1, bf16_t* __restrict__ f2, bf16_t* __restrict__ f3,
    bf16_t* __restrict__ e1, bf16_t* __restrict__ e2, bf16_t* __restrict__ e3,
    bf16_t* __restrict__ wi1, bf16_t* __restrict__ wi2, bf16_t* __restrict__ wi3,
    bf16_t* __restrict__ wh1, bf16_t* __restrict__ wh2, bf16_t* __restrict__ wh3,
    bf16_t* __restrict__ pw1, bf16_t* __restrict__ pw2,
    double* __restrict__ bihd, double* __restrict__ bhhd,
    double* __restrict__ pbd,  double* __restrict__ hf0)
{
    // runtime dtype detection on feat (~N(0,1)): bf16 buffer -> low u16 of a
    // u32 is a plausible bf16 (~128/128 hits); f32 -> uniform bits (~15/128).
    __shared__ int s_cnt;
    if (threadIdx.x == 0) s_cnt = 0;
    __syncthreads();
    if (threadIdx.x < 128) {
        unsigned w = ((const unsigned*)feat)[threadIdx.x];
        unsigned e = (w >> 7) & 0xFFu;
        if (e >= 0x68u && e <= 0x85u) atomicAdd(&s_cnt, 1);
    }
    __syncthreads();
    const int isf32 = (s_cnt < 96) ? 1 : 0;
    if (blockIdx.x == 0 && threadIdx.x == 0) *flag = isf32;

    const long NF = (long)B_ * H_;
    const long NP = (long)V_ * H_;
    const long W_total = NF + NF + NW_ + NW_ + NP + 3 * H_ + 3 * H_ + V_;
    for (long g = blockIdx.x * 256L + threadIdx.x; g < W_total;
         g += (long)gridDim.x * 256L) {
        long i = g;
        if (i < NF) {
            float v = ld_in(feat, i, isf32);
            hf0[i] = (double)v;
            split3f(v, &f1[i], &f2[i], &f3[i]);
            continue;
        }
        i -= NF;
        if (i < NF) {   // embed row 0 (<SOS>) broadcast over batch
            float v = ld_in(embed, i & (H_ - 1), isf32);
            split3f(v, &e1[i], &e2[i], &e3[i]);
            continue;
        }
        i -= NF;
        if (i < NW_) { split3f(ld_in(wih, i, isf32), &wi1[i], &wi2[i], &wi3[i]); continue; }
        i -= NW_;
        if (i < NW_) { split3f(ld_in(whh, i, isf32), &wh1[i], &wh2[i], &wh3[i]); continue; }
        i -= NW_;
        if (i < NP) {
            float v = ld_in(pw, i, isf32);
            bf16_t a = (bf16_t)v;
            pw1[i] = a; pw2[i] = (bf16_t)(v - (float)a);
            continue;
        }
        i -= NP;
        if (i < 3 * H_) { bihd[i] = (double)ld_in(bih, i, isf32); continue; }
        i -= 3 * H_;
        if (i < 3 * H_) { bhhd[i] = (double)ld_in(bhh, i, isf32); continue; }
        i -= 3 * H_;
        if (i < V_) { pbd[i] = (double)ld_in(pb, i, isf32); }
    }
}

// ---------------------------------------------------------------------------
// One wave: [16m x 16v] logits tile of h @ pw^T + pb at time column tcol.
// Non-amplified: 2-split h x 2-split pw is plenty (rel ~2^-18).
__device__ __forceinline__ void proj_tile(
    int mt, int nt,
    const bf16_t* __restrict__ a1p, const bf16_t* __restrict__ a2p,
    const bf16_t* __restrict__ pw1, const bf16_t* __restrict__ pw2,
    const double* __restrict__ pbd,
    void* __restrict__ outp, int isf32, int tcol, int ln, int quad)
{
    const int m0 = mt * 16;
    const int v = nt * 16 + ln;
    const int vr = v < V_ ? v : V_ - 1;
    const bf16_t* a1 = a1p + (long)(m0 + ln) * H_ + quad * 8;
    const bf16_t* a2 = a2p + (long)(m0 + ln) * H_ + quad * 8;
    const bf16_t* b1 = pw1 + (long)vr * H_ + quad * 8;
    const bf16_t* b2 = pw2 + (long)vr * H_ + quad * 8;
    f32x4 acc = {0.f, 0.f, 0.f, 0.f};
    for (int k = 0; k < H_; k += 32) {
        bf16x8 va1 = *(const bf16x8*)(a1 + k);
        bf16x8 va2 = *(const bf16x8*)(a2 + k);
        bf16x8 vb1 = *(const bf16x8*)(b1 + k);
        bf16x8 vb2 = *(const bf16x8*)(b2 + k);
        acc = MFMA(va1, vb2, acc);
        acc = MFMA(va2, vb1, acc);
        acc = MFMA(va1, vb1, acc);
    }
    if (v < V_) {
        const double pbv = pbd[v];
        #pragma unroll
        for (int r = 0; r < 4; ++r) {
            const int m = m0 + quad * 4 + r;
            const long idx = ((long)m * V_ + v) * T_ + tcol;
            const float val = (float)((double)acc[r] + pbv);
            if (isf32) ((float*)outp)[idx] = val;
            else       ((bf16_t*)outp)[idx] = (bf16_t)val;
        }
    }
}

// ---------------------------------------------------------------------------
// GRU step (grid y<4) + fused projection of the step's input h (y==4).
__global__ __launch_bounds__(256) void step_kernel(
    const bf16_t* __restrict__ x1, const bf16_t* __restrict__ x2,
    const bf16_t* __restrict__ x3,
    const bf16_t* __restrict__ h1, const bf16_t* __restrict__ h2,
    const bf16_t* __restrict__ h3,
    const double* __restrict__ hf_in,
    const bf16_t* __restrict__ wi1, const bf16_t* __restrict__ wi2,
    const bf16_t* __restrict__ wi3,
    const bf16_t* __restrict__ wh1, const bf16_t* __restrict__ wh2,
    const bf16_t* __restrict__ wh3,
    const double* __restrict__ bihd, const double* __restrict__ bhhd,
    double* __restrict__ hf_out,
    bf16_t* __restrict__ o1, bf16_t* __restrict__ o2, bf16_t* __restrict__ o3,
    const bf16_t* __restrict__ pw1, const bf16_t* __restrict__ pw2,
    const double* __restrict__ pbd,
    void* __restrict__ outp, const int* __restrict__ flag, int tcol)
{
    const int lane = threadIdx.x & 63;
    const int wave = threadIdx.x >> 6;
    const int ln   = lane & 15;
    const int quad = lane >> 4;

    if (blockIdx.y == 4) {
        if (tcol < 0) return;                  // s==0: input is embed, skip
        const int w = blockIdx.x * 4 + wave;   // 0..127
        const int mt = w >> 3, nt = w & 7;
        if (nt == 7) return;
        proj_tile(mt, nt, x1, x2, pw1, pw2, pbd, outp, *flag, tcol, ln, quad);
        return;
    }

    const int j0 = blockIdx.x * 16;
    const int m0 = blockIdx.y * 64 + wave * 16;

    const long aoff = (long)(m0 + ln) * H_ + quad * 8;
    const bf16_t* xr1 = x1 + aoff;
    const bf16_t* xr2 = x2 + aoff;
    const bf16_t* xr3 = x3 + aoff;
    const bf16_t* hr1 = h1 + aoff;
    const bf16_t* hr2 = h2 + aoff;
    const bf16_t* hr3 = h3 + aoff;
    // W row offsets for gates r,z,n (rows g*512 + j0+ln), 8 consecutive k
    long wrow[3];
    #pragma unroll
    for (int g = 0; g < 3; ++g)
        wrow[g] = (long)(g * H_ + j0 + ln) * H_ + quad * 8;

    double dgi[3][4] = {};   // i_r, i_z, i_n
    double dgh[3][4] = {};   // h_r, h_z, h_n

    for (int k = 0; k < H_; k += 32) {
        bf16x8 ax1 = *(const bf16x8*)(xr1 + k);
        bf16x8 ax2 = *(const bf16x8*)(xr2 + k);
        bf16x8 ax3 = *(const bf16x8*)(xr3 + k);
        bf16x8 ah1 = *(const bf16x8*)(hr1 + k);
        bf16x8 ah2 = *(const bf16x8*)(hr2 + k);
        bf16x8 ah3 = *(const bf16x8*)(hr3 + k);
        #pragma unroll
        for (int g = 0; g < 3; ++g) {
            bf16x8 bi1 = *(const bf16x8*)(wi1 + wrow[g] + k);
            bf16x8 bi2 = *(const bf16x8*)(wi2 + wrow[g] + k);
            bf16x8 bi3 = *(const bf16x8*)(wi3 + wrow[g] + k);
            bf16x8 bh1 = *(const bf16x8*)(wh1 + wrow[g] + k);
            bf16x8 bh2 = *(const bf16x8*)(wh2 + wrow[g] + k);
            bf16x8 bh3 = *(const bf16x8*)(wh3 + wrow[g] + k);
            // zero-init chunk accumulators; smallest terms first
            f32x4 ti = {0.f, 0.f, 0.f, 0.f};
            ti = MFMA(ax1, bi3, ti);
            ti = MFMA(ax2, bi2, ti);
            ti = MFMA(ax3, bi1, ti);
            ti = MFMA(ax1, bi2, ti);
            ti = MFMA(ax2, bi1, ti);
            ti = MFMA(ax1, bi1, ti);
            f32x4 th = {0.f, 0.f, 0.f, 0.f};
            th = MFMA(ah1, bh3, th);
            th = MFMA(ah2, bh2, th);
            th = MFMA(ah3, bh1, th);
            th = MFMA(ah1, bh2, th);
            th = MFMA(ah2, bh1, th);
            th = MFMA(ah1, bh1, th);
            #pragma unroll
            for (int r = 0; r < 4; ++r) {
                dgi[g][r] += (double)ti[r];
                dgh[g][r] += (double)th[r];
            }
        }
    }

    const int j = j0 + ln;
    const double bir = bihd[j],            bhr = bhhd[j];
    const double biz = bihd[H_ + j],       bhz = bhhd[H_ + j];
    const double bin_ = bihd[2 * H_ + j],  bhn = bhhd[2 * H_ + j];

    #pragma unroll
    for (int r = 0; r < 4; ++r) {
        const int m = m0 + quad * 4 + r;
        const double rg = 1.0 / (1.0 + exp(-(dgi[0][r] + bir + dgh[0][r] + bhr)));
        const double zg = 1.0 / (1.0 + exp(-(dgi[1][r] + biz + dgh[1][r] + bhz)));
        const double pre = dgi[2][r] + bin_ + rg * (dgh[2][r] + bhn);
        const double ng = tanh(pre);
        const double hp = hf_in[(long)m * H_ + j];
        const double hv = (1.0 - zg) * ng + zg * hp;
        const long oi = (long)m * H_ + j;
        hf_out[oi] = hv;
        split3d(hv, &o1[oi], &o2[oi], &o3[oi]);
    }
}

// Tail: project h_200 at time column 199.
__global__ __launch_bounds__(256) void proj_tail_kernel(
    const bf16_t* __restrict__ a1, const bf16_t* __restrict__ a2,
    const bf16_t* __restrict__ pw1, const bf16_t* __restrict__ pw2,
    const double* __restrict__ pbd,
    void* __restrict__ outp, const int* __restrict__ flag)
{
    const int lane = threadIdx.x & 63;
    const int wave = threadIdx.x >> 6;
    const int w = blockIdx.x * 4 + wave;
    const int mt = w >> 3, nt = w & 7;
    if (nt == 7) return;
    proj_tile(mt, nt, a1, a2, pw1, pw2, pbd, outp, *flag, T_ - 1,
              lane & 15, lane >> 4);
}

// ---------------------------------------------------------------------------
extern "C" void kernel_launch(void* const* d_in, const int* in_sizes, int n_in,
                              void* d_out, int out_size, void* d_ws, size_t ws_size,
                              hipStream_t stream) {
    char* ws = (char*)d_ws;
    const long NFb = (long)B_ * H_ * sizeof(bf16_t);   // 262144
    const long NWb = (long)NW_ * sizeof(bf16_t);       // 1572864
    long off = 0;
    int*    flag = (int*)(ws + off);        off += 256;
    bf16_t* f1 = (bf16_t*)(ws + off);       off += NFb;
    bf16_t* f2 = (bf16_t*)(ws + off);       off += NFb;
    bf16_t* f3 = (bf16_t*)(ws + off);       off += NFb;
    bf16_t* e1 = (bf16_t*)(ws + off);       off += NFb;
    bf16_t* e2 = (bf16_t*)(ws + off);       off += NFb;
    bf16_t* e3 = (bf16_t*)(ws + off);       off += NFb;
    bf16_t* xA1 = (bf16_t*)(ws + off);      off += NFb;
    bf16_t* xA2 = (bf16_t*)(ws + off);      off += NFb;
    bf16_t* xA3 = (bf16_t*)(ws + off);      off += NFb;
    bf16_t* xB1 = (bf16_t*)(ws + off);      off += NFb;
    bf16_t* xB2 = (bf16_t*)(ws + off);      off += NFb;
    bf16_t* xB3 = (bf16_t*)(ws + off);      off += NFb;
    bf16_t* wi1 = (bf16_t*)(ws + off);      off += NWb;
    bf16_t* wi2 = (bf16_t*)(ws + off);      off += NWb;
    bf16_t* wi3 = (bf16_t*)(ws + off);      off += NWb;
    bf16_t* wh1 = (bf16_t*)(ws + off);      off += NWb;
    bf16_t* wh2 = (bf16_t*)(ws + off);      off += NWb;
    bf16_t* wh3 = (bf16_t*)(ws + off);      off += NWb;
    bf16_t* pw1 = (bf16_t*)(ws + off);      off += (long)V_ * H_ * 2;
    bf16_t* pw2 = (bf16_t*)(ws + off);      off += (long)V_ * H_ * 2;
    double* bihd = (double*)(ws + off);     off += 3 * H_ * 8;
    double* bhhd = (double*)(ws + off);     off += 3 * H_ * 8;
    double* pbd  = (double*)(ws + off);     off += 1024;
    double* hfA  = (double*)(ws + off);     off += (long)B_ * H_ * 8;
    double* hfB  = (double*)(ws + off);     off += (long)B_ * H_ * 8;

    convert_kernel<<<1024, 256, 0, stream>>>(
        d_in[0], d_in[1], d_in[2], d_in[3], d_in[4], d_in[5], d_in[6], d_in[7],
        flag, f1, f2, f3, e1, e2, e3,
        wi1, wi2, wi3, wh1, wh2, wh3, pw1, pw2, bihd, bhhd, pbd, hfA);

    bf16_t* xs1[2] = {xA1, xB1};
    bf16_t* xs2[2] = {xA2, xB2};
    bf16_t* xs3[2] = {xA3, xB3};
    double* hf[2]  = {hfA, hfB};
    for (int s = 0; s < T_; ++s) {
        const int pi = s & 1, po = (s + 1) & 1;
        const bf16_t* cx1 = (s == 0) ? e1 : xs1[pi];
        const bf16_t* cx2 = (s == 0) ? e2 : xs2[pi];
        const bf16_t* cx3 = (s == 0) ? e3 : xs3[pi];
        const bf16_t* ch1 = (s == 0) ? f1 : xs1[pi];
        const bf16_t* ch2 = (s == 0) ? f2 : xs2[pi];
        const bf16_t* ch3 = (s == 0) ? f3 : xs3[pi];
        step_kernel<<<dim3(32, 5), 256, 0, stream>>>(
            cx1, cx2, cx3, ch1, ch2, ch3, hf[pi],
            wi1, wi2, wi3, wh1, wh2, wh3, bihd, bhhd,
            hf[po], xs1[po], xs2[po], xs3[po],
            pw1, pw2, pbd, d_out, flag, s - 1);
    }
    proj_tail_kernel<<<32, 256, 0, stream>>>(
        xs1[0], xs2[0], pw1, pw2, pbd, d_out, flag);
}